// Round 1
// baseline (1873.262 us; speedup 1.0000x reference)
//
#include <hip/hip_runtime.h>
#include <hip/hip_bf16.h>

typedef unsigned short u16;
typedef __bf16 bf16x8 __attribute__((ext_vector_type(8)));
typedef float f32x4 __attribute__((ext_vector_type(4)));

#define NTOK 524288      // B*H*W tokens
#define NWIN 8192        // B * 1024 windows
#define SCALE 0.20412414523193154f   // 24^-0.5

__device__ inline u16 f2bf(float f) {
    __hip_bfloat16 h = __float2bfloat16(f);
    return __builtin_bit_cast(u16, h);
}
__device__ inline bf16x8 ldfrag(const u16* p) {
    return __builtin_bit_cast(bf16x8, *reinterpret_cast<const int4*>(p));
}
__device__ inline bf16x8 zfrag() {
    return __builtin_bit_cast(bf16x8, make_int4(0, 0, 0, 0));
}
__device__ inline int region_of(int wh, int ww, int n) {
    int hr = wh * 8 + (n >> 3);
    int wc = ww * 8 + (n & 7);
    int rh = (hr < 248) ? 0 : (hr < 252 ? 1 : 2);
    int rw = (wc < 248) ? 0 : (wc < 252 ? 1 : 2);
    return rh * 3 + rw;
}

// ---------------- kernel 0: weight convert/transpose to bf16 ----------------
// qkvT: [288][104 pad]  (q columns pre-scaled by SCALE)
// projT:[96][104 pad]   w1T:[384][96]   w2T:[96][384]
__global__ __launch_bounds__(256) void k_convert(
        const float* __restrict__ qkv_w, const float* __restrict__ proj_w,
        const float* __restrict__ w1, const float* __restrict__ w2,
        u16* __restrict__ qkvT, u16* __restrict__ projT,
        u16* __restrict__ w1T, u16* __restrict__ w2T) {
    int idx = blockIdx.x * 256 + threadIdx.x;
    if (idx < 288 * 96) {
        int n = idx / 96, k = idx % 96;
        float v = qkv_w[k * 288 + n];
        if (n < 96) v *= SCALE;
        qkvT[n * 104 + k] = f2bf(v);
    }
    if (idx < 96 * 96) {
        int n = idx / 96, k = idx % 96;
        projT[n * 104 + k] = f2bf(proj_w[k * 96 + n]);
    }
    if (idx < 384 * 96) {
        int n = idx / 96, k = idx % 96;
        w1T[n * 96 + k] = f2bf(w1[k * 384 + n]);
    }
    if (idx < 96 * 384) {
        int n = idx / 384, k = idx % 384;
        w2T[n * 384 + k] = f2bf(w2[k * 96 + n]);
    }
}

// ---------------- LN core: one wave per 96-channel token ----------------
__device__ inline void ln_core(const float* __restrict__ row,
                               const float* __restrict__ g,
                               const float* __restrict__ b,
                               int lane, float& y0, float& y1) {
    float v0 = row[lane];
    float v1 = (lane < 32) ? row[64 + lane] : 0.0f;
    float s = v0 + v1;
    float q = v0 * v0 + v1 * v1;
#pragma unroll
    for (int m = 1; m < 64; m <<= 1) { s += __shfl_xor(s, m); q += __shfl_xor(q, m); }
    float mean = s * (1.0f / 96.0f);
    float var  = q * (1.0f / 96.0f) - mean * mean;
    float rstd = rsqrtf(var + 1e-5f);
    y0 = (v0 - mean) * rstd * g[lane] + b[lane];
    y1 = (lane < 32) ? (v1 - mean) * rstd * g[64 + lane] + b[64 + lane] : 0.0f;
}

// ---------------- kernel 1: LN1 + roll(-4,-4) + window partition ----------------
__global__ __launch_bounds__(256) void k_ln1(const float* __restrict__ x,
                                             const float* __restrict__ g,
                                             const float* __restrict__ b,
                                             u16* __restrict__ yw) {
    int wtok = blockIdx.x * 4 + (threadIdx.x >> 6);
    int lane = threadIdx.x & 63;
    int win = wtok >> 6, n = wtok & 63;
    int b_ = win >> 10, wh = (win >> 5) & 31, ww = win & 31;
    int h0 = (wh * 8 + (n >> 3) + 4) & 255;
    int w0 = (ww * 8 + (n & 7) + 4) & 255;
    const float* row = x + ((size_t)(b_ * 256 + h0) * 256 + w0) * 96;
    float y0, y1;
    ln_core(row, g, b, lane, y0, y1);
    u16* out = yw + (size_t)wtok * 96;
    out[lane] = f2bf(y0);
    if (lane < 32) out[64 + lane] = f2bf(y1);
}

// ---------------- kernel 2: QKV GEMM  (M=524288, K=96, N=288) ----------------
__global__ __launch_bounds__(256) void k_qkv(const u16* __restrict__ yw,
                                             const u16* __restrict__ wT,
                                             const float* __restrict__ bias,
                                             u16* __restrict__ qkv) {
    __shared__ __align__(16) u16 wlds[288 * 104];
    {
        const int4* src = reinterpret_cast<const int4*>(wT);
        int4* dst = reinterpret_cast<int4*>(wlds);
        for (int i = threadIdx.x; i < 288 * 104 / 8; i += 256) dst[i] = src[i];
    }
    __syncthreads();
    const int wave = threadIdx.x >> 6, lane = threadIdx.x & 63;
    const int l15 = lane & 15, quad = lane >> 4;
    const int rowbase = blockIdx.x * 128 + wave * 32;
    f32x4 zero = {0.f, 0.f, 0.f, 0.f};
    f32x4 acc[2][18];
#pragma unroll
    for (int mt = 0; mt < 2; mt++)
#pragma unroll
        for (int ct = 0; ct < 18; ct++) acc[mt][ct] = zero;
#pragma unroll
    for (int kb = 0; kb < 96; kb += 32) {
        bf16x8 a0 = ldfrag(yw + (size_t)(rowbase + l15) * 96 + kb + quad * 8);
        bf16x8 a1 = ldfrag(yw + (size_t)(rowbase + 16 + l15) * 96 + kb + quad * 8);
#pragma unroll
        for (int ct = 0; ct < 18; ct++) {
            bf16x8 bf = ldfrag(&wlds[(ct * 16 + l15) * 104 + kb + quad * 8]);
            acc[0][ct] = __builtin_amdgcn_mfma_f32_16x16x32_bf16(a0, bf, acc[0][ct], 0, 0, 0);
            acc[1][ct] = __builtin_amdgcn_mfma_f32_16x16x32_bf16(a1, bf, acc[1][ct], 0, 0, 0);
        }
    }
#pragma unroll
    for (int mt = 0; mt < 2; mt++)
#pragma unroll
        for (int ct = 0; ct < 18; ct++) {
            int col = ct * 16 + l15;
            float bv = bias[col] * (col < 96 ? SCALE : 1.0f);
#pragma unroll
            for (int r = 0; r < 4; r++) {
                int row = rowbase + mt * 16 + quad * 4 + r;
                qkv[(size_t)row * 288 + col] = f2bf(acc[mt][ct][r] + bv);
            }
        }
}

// ---------------- kernel 3: windowed attention (1 block/window, 1 wave/head) ----------------
__global__ __launch_bounds__(256) void k_attn(const u16* __restrict__ qkv,
                                              const float* __restrict__ btab,
                                              u16* __restrict__ aout) {
    __shared__ __align__(16) float blds[900];
    __shared__ __align__(16) u16 vt[4][24 * 72];   // V^T per head, padded stride 72
    __shared__ __align__(16) u16 pm[4][64 * 72];   // P per head, padded stride 72
    const int tid = threadIdx.x;
    for (int i = tid; i < 900; i += 256)
        blds[i] = fminf(fmaxf(btab[i], -5.0f), 5.0f);
    const int head = tid >> 6, lane = tid & 63;
    const int l15 = lane & 15, quad = lane >> 4;
    const int win = blockIdx.x;
    const int wh = (win >> 5) & 31, ww = win & 31;
    const u16* base = qkv + (size_t)win * 64 * 288;
    // stage V^T: vt[head][d][tok]
#pragma unroll
    for (int it = 0; it < 3; it++) {
        int idx = it * 64 + lane;
        int tok = idx / 3, ch = idx - tok * 3;
        int4 raw = *reinterpret_cast<const int4*>(base + tok * 288 + 192 + head * 24 + ch * 8);
        union { int4 v; u16 u[8]; } uu; uu.v = raw;
#pragma unroll
        for (int j = 0; j < 8; j++) vt[head][(ch * 8 + j) * 72 + tok] = uu.u[j];
    }
    __syncthreads();
    // Q (A-op) and K (B-op) fragments; K-dim 24 padded to 32 (quad 3 = zeros)
    bf16x8 aq[4], bk[4];
#pragma unroll
    for (int t = 0; t < 4; t++) {
        if (quad < 3) {
            aq[t] = ldfrag(base + (t * 16 + l15) * 288 + head * 24 + quad * 8);
            bk[t] = ldfrag(base + (t * 16 + l15) * 288 + 96 + head * 24 + quad * 8);
        } else { aq[t] = zfrag(); bk[t] = zfrag(); }
    }
    f32x4 zero = {0.f, 0.f, 0.f, 0.f};
    f32x4 s[4][4];
#pragma unroll
    for (int mt = 0; mt < 4; mt++)
#pragma unroll
        for (int ct = 0; ct < 4; ct++)
            s[mt][ct] = __builtin_amdgcn_mfma_f32_16x16x32_bf16(aq[mt], bk[ct], zero, 0, 0, 0);
    // per-column region ids for this lane
    int regc[4], colr[4], colc[4];
#pragma unroll
    for (int ct = 0; ct < 4; ct++) {
        int col = ct * 16 + l15;
        colr[ct] = col >> 3; colc[ct] = col & 7;
        regc[ct] = region_of(wh, ww, col);
    }
    // mask + bias + clip + row softmax (rows live in 16-lane groups)
#pragma unroll
    for (int mt = 0; mt < 4; mt++) {
#pragma unroll
        for (int r = 0; r < 4; r++) {
            int row = mt * 16 + quad * 4 + r;
            int rr = row >> 3, rc = row & 7;
            int regr = region_of(wh, ww, row);
            float sv[4]; float mx = -1e30f;
#pragma unroll
            for (int ct = 0; ct < 4; ct++) {
                float bias = blds[((rr - colr[ct] + 7) * 15 + (rc - colc[ct] + 7)) * 4 + head];
                float v = (regr == regc[ct])
                        ? fminf(fmaxf(s[mt][ct][r] + bias, -10.0f), 10.0f) : -10.0f;
                sv[ct] = v; mx = fmaxf(mx, v);
            }
#pragma unroll
            for (int m = 1; m < 16; m <<= 1) mx = fmaxf(mx, __shfl_xor(mx, m));
            float sum = 0.f;
#pragma unroll
            for (int ct = 0; ct < 4; ct++) { sv[ct] = __expf(sv[ct] - mx); sum += sv[ct]; }
#pragma unroll
            for (int m = 1; m < 16; m <<= 1) sum += __shfl_xor(sum, m);
            float inv = 1.0f / sum;
#pragma unroll
            for (int ct = 0; ct < 4; ct++)
                pm[head][row * 72 + ct * 16 + l15] = f2bf(sv[ct] * inv);
        }
    }
    __syncthreads();
    // O = P @ V
    f32x4 o[4][2];
#pragma unroll
    for (int mt = 0; mt < 4; mt++) { o[mt][0] = zero; o[mt][1] = zero; }
#pragma unroll
    for (int kb = 0; kb < 2; kb++) {
        bf16x8 ap[4];
#pragma unroll
        for (int mt = 0; mt < 4; mt++)
            ap[mt] = ldfrag(&pm[head][(mt * 16 + l15) * 72 + kb * 32 + quad * 8]);
        bf16x8 bv0 = ldfrag(&vt[head][l15 * 72 + kb * 32 + quad * 8]);
        bf16x8 bv1 = (l15 < 8) ? ldfrag(&vt[head][(16 + l15) * 72 + kb * 32 + quad * 8]) : zfrag();
#pragma unroll
        for (int mt = 0; mt < 4; mt++) {
            o[mt][0] = __builtin_amdgcn_mfma_f32_16x16x32_bf16(ap[mt], bv0, o[mt][0], 0, 0, 0);
            o[mt][1] = __builtin_amdgcn_mfma_f32_16x16x32_bf16(ap[mt], bv1, o[mt][1], 0, 0, 0);
        }
    }
#pragma unroll
    for (int ct2 = 0; ct2 < 2; ct2++) {
        int d = ct2 * 16 + l15;
        if (d < 24) {
#pragma unroll
            for (int mt = 0; mt < 4; mt++)
#pragma unroll
                for (int r = 0; r < 4; r++) {
                    int tok = mt * 16 + quad * 4 + r;
                    aout[((size_t)win * 64 + tok) * 96 + head * 24 + d] = f2bf(o[mt][ct2][r]);
                }
        }
    }
}

// ------- kernel 4: proj GEMM + window reverse + roll(+4,+4) + residual -> x1 (in d_out) -------
__global__ __launch_bounds__(256) void k_proj(const u16* __restrict__ aout,
                                              const u16* __restrict__ wT,
                                              const float* __restrict__ pb,
                                              const float* __restrict__ x,
                                              float* __restrict__ x1) {
    __shared__ __align__(16) u16 wlds[96 * 104];
    {
        const int4* src = reinterpret_cast<const int4*>(wT);
        int4* dst = reinterpret_cast<int4*>(wlds);
        for (int i = threadIdx.x; i < 96 * 104 / 8; i += 256) dst[i] = src[i];
    }
    __syncthreads();
    const int wave = threadIdx.x >> 6, lane = threadIdx.x & 63;
    const int l15 = lane & 15, quad = lane >> 4;
    const int rowbase = blockIdx.x * 128 + wave * 32;
    f32x4 zero = {0.f, 0.f, 0.f, 0.f};
    f32x4 acc[2][6];
#pragma unroll
    for (int mt = 0; mt < 2; mt++)
#pragma unroll
        for (int ct = 0; ct < 6; ct++) acc[mt][ct] = zero;
#pragma unroll
    for (int kb = 0; kb < 96; kb += 32) {
        bf16x8 a0 = ldfrag(aout + (size_t)(rowbase + l15) * 96 + kb + quad * 8);
        bf16x8 a1 = ldfrag(aout + (size_t)(rowbase + 16 + l15) * 96 + kb + quad * 8);
#pragma unroll
        for (int ct = 0; ct < 6; ct++) {
            bf16x8 bf = ldfrag(&wlds[(ct * 16 + l15) * 104 + kb + quad * 8]);
            acc[0][ct] = __builtin_amdgcn_mfma_f32_16x16x32_bf16(a0, bf, acc[0][ct], 0, 0, 0);
            acc[1][ct] = __builtin_amdgcn_mfma_f32_16x16x32_bf16(a1, bf, acc[1][ct], 0, 0, 0);
        }
    }
#pragma unroll
    for (int mt = 0; mt < 2; mt++)
#pragma unroll
        for (int r = 0; r < 4; r++) {
            int wtok = rowbase + mt * 16 + quad * 4 + r;
            int win = wtok >> 6, n = wtok & 63;
            int b_ = win >> 10, wh = (win >> 5) & 31, ww = win & 31;
            int h0 = (wh * 8 + (n >> 3) + 4) & 255;
            int w0 = (ww * 8 + (n & 7) + 4) & 255;
            size_t obase = ((size_t)(b_ * 256 + h0) * 256 + w0) * 96;
#pragma unroll
            for (int ct = 0; ct < 6; ct++) {
                int col = ct * 16 + l15;
                x1[obase + col] = acc[mt][ct][r] + pb[col] + x[obase + col];
            }
        }
}

// ---------------- kernel 5: LN2 ----------------
__global__ __launch_bounds__(256) void k_ln2(const float* __restrict__ x1,
                                             const float* __restrict__ g,
                                             const float* __restrict__ b,
                                             u16* __restrict__ hn) {
    int tok = blockIdx.x * 4 + (threadIdx.x >> 6);
    int lane = threadIdx.x & 63;
    const float* row = x1 + (size_t)tok * 96;
    float y0, y1;
    ln_core(row, g, b, lane, y0, y1);
    u16* out = hn + (size_t)tok * 96;
    out[lane] = f2bf(y0);
    if (lane < 32) out[64 + lane] = f2bf(y1);
}

// ------- kernel 6: fused MLP: gelu(h@W1+b1)@W2+b2 + x1 -> d_out (mid tile in LDS) -------
__global__ __launch_bounds__(256) void k_mlp(const u16* __restrict__ hn,
                                             const u16* __restrict__ w1T,
                                             const float* __restrict__ b1,
                                             const u16* __restrict__ w2T,
                                             const float* __restrict__ b2,
                                             float* __restrict__ io) {
    __shared__ __align__(16) u16 mid[64 * 392];   // 64 tokens x 384, stride 392
    const int wave = threadIdx.x >> 6, lane = threadIdx.x & 63;
    const int l15 = lane & 15, quad = lane >> 4;
    const int rowbase = blockIdx.x * 64 + wave * 16;
    f32x4 zero = {0.f, 0.f, 0.f, 0.f};
    f32x4 acc[24];
#pragma unroll
    for (int ct = 0; ct < 24; ct++) acc[ct] = zero;
#pragma unroll
    for (int kb = 0; kb < 96; kb += 32) {
        bf16x8 a = ldfrag(hn + (size_t)(rowbase + l15) * 96 + kb + quad * 8);
#pragma unroll
        for (int ct = 0; ct < 24; ct++) {
            bf16x8 bf = ldfrag(w1T + (ct * 16 + l15) * 96 + kb + quad * 8);
            acc[ct] = __builtin_amdgcn_mfma_f32_16x16x32_bf16(a, bf, acc[ct], 0, 0, 0);
        }
    }
#pragma unroll
    for (int ct = 0; ct < 24; ct++) {
        int col = ct * 16 + l15;
        float bb = b1[col];
#pragma unroll
        for (int r = 0; r < 4; r++) {
            float v = acc[ct][r] + bb;
            float gl = 0.5f * v * (1.0f + erff(v * 0.70710678118654752f));
            mid[(wave * 16 + quad * 4 + r) * 392 + col] = f2bf(gl);
        }
    }
    __syncthreads();
    f32x4 acc2[6];
#pragma unroll
    for (int ct = 0; ct < 6; ct++) acc2[ct] = zero;
#pragma unroll
    for (int kb2 = 0; kb2 < 12; kb2++) {
        bf16x8 a = ldfrag(&mid[(wave * 16 + l15) * 392 + kb2 * 32 + quad * 8]);
#pragma unroll
        for (int ct = 0; ct < 6; ct++) {
            bf16x8 bf = ldfrag(w2T + (ct * 16 + l15) * 384 + kb2 * 32 + quad * 8);
            acc2[ct] = __builtin_amdgcn_mfma_f32_16x16x32_bf16(a, bf, acc2[ct], 0, 0, 0);
        }
    }
#pragma unroll
    for (int ct = 0; ct < 6; ct++) {
        int col = ct * 16 + l15;
        float bb = b2[col];
#pragma unroll
        for (int r = 0; r < 4; r++) {
            size_t o = (size_t)(rowbase + quad * 4 + r) * 96 + col;
            io[o] = acc2[ct][r] + bb + io[o];
        }
    }
}

extern "C" void kernel_launch(void* const* d_in, const int* in_sizes, int n_in,
                              void* d_out, int out_size, void* d_ws, size_t ws_size,
                              hipStream_t stream) {
    const float* x      = (const float*)d_in[0];
    const float* n1g    = (const float*)d_in[1];
    const float* n1b    = (const float*)d_in[2];
    const float* qkv_w  = (const float*)d_in[3];
    const float* qkv_b  = (const float*)d_in[4];
    const float* btab   = (const float*)d_in[5];
    const float* proj_w = (const float*)d_in[6];
    const float* proj_b = (const float*)d_in[7];
    const float* n2g    = (const float*)d_in[8];
    const float* n2b    = (const float*)d_in[9];
    const float* w1     = (const float*)d_in[10];
    const float* b1     = (const float*)d_in[11];
    const float* w2     = (const float*)d_in[12];
    const float* b2     = (const float*)d_in[13];
    float* out = (float*)d_out;
    char* ws = (char*)d_ws;

    u16* qkvb  = (u16*)(ws);                  // 524288*288*2 = 301,989,888
    u16* tokb  = (u16*)(ws + 301989888);      // 524288*96*2  = 100,663,296 (yw -> attn_out -> h_norm)
    u16* qkvT  = (u16*)(ws + 402653184);      // 288*104*2 = 59,904
    u16* projT = (u16*)(ws + 402713088);      // 96*104*2  = 19,968
    u16* w1T   = (u16*)(ws + 402733056);      // 384*96*2  = 73,728
    u16* w2T   = (u16*)(ws + 402806784);      // 96*384*2  = 73,728  (end 402,880,512)

    k_convert<<<144, 256, 0, stream>>>(qkv_w, proj_w, w1, w2, qkvT, projT, w1T, w2T);
    k_ln1<<<NTOK / 4, 256, 0, stream>>>(x, n1g, n1b, tokb);
    k_qkv<<<NTOK / 128, 256, 0, stream>>>(tokb, qkvT, qkv_b, qkvb);
    k_attn<<<NWIN, 256, 0, stream>>>(qkvb, btab, tokb);
    k_proj<<<NTOK / 128, 256, 0, stream>>>(tokb, projT, proj_b, x, out);
    k_ln2<<<NTOK / 4, 256, 0, stream>>>(out, n2g, n2b, tokb);
    k_mlp<<<NTOK / 64, 256, 0, stream>>>(tokb, w1T, b1, w2T, b2, out);
}

// Round 2
// 1213.460 us; speedup vs baseline: 1.5437x; 1.5437x over previous
//
#include <hip/hip_runtime.h>
#include <hip/hip_bf16.h>

typedef unsigned short u16;
typedef __bf16 bf16x8 __attribute__((ext_vector_type(8)));
typedef float f32x4 __attribute__((ext_vector_type(4)));

#define NTOK 524288      // B*H*W tokens
#define NWIN 8192        // B * 1024 windows
#define SCALE 0.20412414523193154f   // 24^-0.5

__device__ inline u16 f2bf(float f) {
    __hip_bfloat16 h = __float2bfloat16(f);
    return __builtin_bit_cast(u16, h);
}
__device__ inline float bf2f(u16 u) {
    return __bfloat162float(__builtin_bit_cast(__hip_bfloat16, u));
}
__device__ inline bf16x8 ldfrag(const u16* p) {
    return __builtin_bit_cast(bf16x8, *reinterpret_cast<const int4*>(p));
}
__device__ inline bf16x8 zfrag() {
    return __builtin_bit_cast(bf16x8, make_int4(0, 0, 0, 0));
}
__device__ inline int region_of(int wh, int ww, int n) {
    int hr = wh * 8 + (n >> 3);
    int wc = ww * 8 + (n & 7);
    int rh = (hr < 248) ? 0 : (hr < 252 ? 1 : 2);
    int rw = (wc < 248) ? 0 : (wc < 252 ? 1 : 2);
    return rh * 3 + rw;
}

// ---------------- kernel 0: weight convert/transpose to bf16 (unpadded) ----------------
// qkvT:[288][96] (q cols pre-scaled)  projT:[96][96]  w1T:[384][96]  w2T:[96][384]
__global__ __launch_bounds__(256) void k_convert(
        const float* __restrict__ qkv_w, const float* __restrict__ proj_w,
        const float* __restrict__ w1, const float* __restrict__ w2,
        u16* __restrict__ qkvT, u16* __restrict__ projT,
        u16* __restrict__ w1T, u16* __restrict__ w2T) {
    int idx = blockIdx.x * 256 + threadIdx.x;
    if (idx < 288 * 96) {
        int n = idx / 96, k = idx % 96;
        float v = qkv_w[k * 288 + n];
        if (n < 96) v *= SCALE;
        qkvT[n * 96 + k] = f2bf(v);
    }
    if (idx < 96 * 96) {
        int n = idx / 96, k = idx % 96;
        projT[n * 96 + k] = f2bf(proj_w[k * 96 + n]);
    }
    if (idx < 384 * 96) {
        int n = idx / 96, k = idx % 96;
        w1T[n * 96 + k] = f2bf(w1[k * 384 + n]);
    }
    if (idx < 96 * 384) {
        int n = idx / 384, k = idx % 384;
        w2T[n * 384 + k] = f2bf(w2[k * 96 + n]);
    }
}

// ---------------- LN core: one wave per 96-channel token ----------------
__device__ inline void ln_core(const float* __restrict__ row,
                               const float* __restrict__ g,
                               const float* __restrict__ b,
                               int lane, float& y0, float& y1) {
    float v0 = row[lane];
    float v1 = (lane < 32) ? row[64 + lane] : 0.0f;
    float s = v0 + v1;
    float q = v0 * v0 + v1 * v1;
#pragma unroll
    for (int m = 1; m < 64; m <<= 1) { s += __shfl_xor(s, m); q += __shfl_xor(q, m); }
    float mean = s * (1.0f / 96.0f);
    float var  = q * (1.0f / 96.0f) - mean * mean;
    float rstd = rsqrtf(var + 1e-5f);
    y0 = (v0 - mean) * rstd * g[lane] + b[lane];
    y1 = (lane < 32) ? (v1 - mean) * rstd * g[64 + lane] + b[64 + lane] : 0.0f;
}

// ---------------- kernel 1: LN1 + roll(-4,-4) + window partition ----------------
__global__ __launch_bounds__(256) void k_ln1(const float* __restrict__ x,
                                             const float* __restrict__ g,
                                             const float* __restrict__ b,
                                             u16* __restrict__ yw) {
    int wtok = blockIdx.x * 4 + (threadIdx.x >> 6);
    int lane = threadIdx.x & 63;
    int win = wtok >> 6, n = wtok & 63;
    int b_ = win >> 10, wh = (win >> 5) & 31, ww = win & 31;
    int h0 = (wh * 8 + (n >> 3) + 4) & 255;
    int w0 = (ww * 8 + (n & 7) + 4) & 255;
    const float* row = x + ((size_t)(b_ * 256 + h0) * 256 + w0) * 96;
    float y0, y1;
    ln_core(row, g, b, lane, y0, y1);
    u16* out = yw + (size_t)wtok * 96;
    out[lane] = f2bf(y0);
    if (lane < 32) out[64 + lane] = f2bf(y1);
}

// ---------------- kernel 2: QKV GEMM  (M=524288, K=96, N=288) ----------------
__global__ __launch_bounds__(256) void k_qkv(const u16* __restrict__ yw,
                                             const u16* __restrict__ wT,
                                             const float* __restrict__ bias,
                                             u16* __restrict__ qkv) {
    __shared__ __align__(16) u16 wlds[288 * 104];   // padded stride 104 (208B = 13x16B)
    {
        const int4* src = reinterpret_cast<const int4*>(wT);
        for (int i = threadIdx.x; i < 288 * 12; i += 256) {
            int row = i / 12, j = i - row * 12;
            *reinterpret_cast<int4*>(&wlds[row * 104 + j * 8]) = src[i];
        }
    }
    __syncthreads();
    const int wave = threadIdx.x >> 6, lane = threadIdx.x & 63;
    const int l15 = lane & 15, quad = lane >> 4;
    const int rowbase = blockIdx.x * 128 + wave * 32;
    f32x4 zero = {0.f, 0.f, 0.f, 0.f};
    f32x4 acc[2][18];
#pragma unroll
    for (int mt = 0; mt < 2; mt++)
#pragma unroll
        for (int ct = 0; ct < 18; ct++) acc[mt][ct] = zero;
#pragma unroll
    for (int kb = 0; kb < 96; kb += 32) {
        bf16x8 a0 = ldfrag(yw + (size_t)(rowbase + l15) * 96 + kb + quad * 8);
        bf16x8 a1 = ldfrag(yw + (size_t)(rowbase + 16 + l15) * 96 + kb + quad * 8);
#pragma unroll
        for (int ct = 0; ct < 18; ct++) {
            bf16x8 bf = ldfrag(&wlds[(ct * 16 + l15) * 104 + kb + quad * 8]);
            acc[0][ct] = __builtin_amdgcn_mfma_f32_16x16x32_bf16(a0, bf, acc[0][ct], 0, 0, 0);
            acc[1][ct] = __builtin_amdgcn_mfma_f32_16x16x32_bf16(a1, bf, acc[1][ct], 0, 0, 0);
        }
    }
#pragma unroll
    for (int mt = 0; mt < 2; mt++)
#pragma unroll
        for (int ct = 0; ct < 18; ct++) {
            int col = ct * 16 + l15;
            float bv = bias[col] * (col < 96 ? SCALE : 1.0f);
#pragma unroll
            for (int r = 0; r < 4; r++) {
                int row = rowbase + mt * 16 + quad * 4 + r;
                qkv[(size_t)row * 288 + col] = f2bf(acc[mt][ct][r] + bv);
            }
        }
}

// ---------------- kernel 3: windowed attention (1 block/window, 1 wave/head) ----------------
__global__ __launch_bounds__(256) void k_attn(const u16* __restrict__ qkv,
                                              const float* __restrict__ btab,
                                              u16* __restrict__ aout) {
    __shared__ __align__(16) float blds[900];
    __shared__ __align__(16) u16 vt[4][24 * 72];   // V^T per head, padded stride 72
    __shared__ __align__(16) u16 pm[4][64 * 72];   // P per head, padded stride 72
    const int tid = threadIdx.x;
    for (int i = tid; i < 900; i += 256)
        blds[i] = fminf(fmaxf(btab[i], -5.0f), 5.0f);
    const int head = tid >> 6, lane = tid & 63;
    const int l15 = lane & 15, quad = lane >> 4;
    const int win = blockIdx.x;
    const int wh = (win >> 5) & 31, ww = win & 31;
    const u16* base = qkv + (size_t)win * 64 * 288;
    // stage V^T: vt[head][d][tok]
#pragma unroll
    for (int it = 0; it < 3; it++) {
        int idx = it * 64 + lane;
        int tok = idx / 3, ch = idx - tok * 3;
        int4 raw = *reinterpret_cast<const int4*>(base + tok * 288 + 192 + head * 24 + ch * 8);
        union { int4 v; u16 u[8]; } uu; uu.v = raw;
#pragma unroll
        for (int j = 0; j < 8; j++) vt[head][(ch * 8 + j) * 72 + tok] = uu.u[j];
    }
    __syncthreads();
    // Q (A-op) and K (B-op) fragments; K-dim 24 padded to 32 (quad 3 = zeros)
    bf16x8 aq[4], bk[4];
#pragma unroll
    for (int t = 0; t < 4; t++) {
        if (quad < 3) {
            aq[t] = ldfrag(base + (t * 16 + l15) * 288 + head * 24 + quad * 8);
            bk[t] = ldfrag(base + (t * 16 + l15) * 288 + 96 + head * 24 + quad * 8);
        } else { aq[t] = zfrag(); bk[t] = zfrag(); }
    }
    f32x4 zero = {0.f, 0.f, 0.f, 0.f};
    f32x4 s[4][4];
#pragma unroll
    for (int mt = 0; mt < 4; mt++)
#pragma unroll
        for (int ct = 0; ct < 4; ct++)
            s[mt][ct] = __builtin_amdgcn_mfma_f32_16x16x32_bf16(aq[mt], bk[ct], zero, 0, 0, 0);
    // per-column region ids for this lane
    int regc[4], colr[4], colc[4];
#pragma unroll
    for (int ct = 0; ct < 4; ct++) {
        int col = ct * 16 + l15;
        colr[ct] = col >> 3; colc[ct] = col & 7;
        regc[ct] = region_of(wh, ww, col);
    }
    // mask + bias + clip + row softmax (rows live in 16-lane groups)
#pragma unroll
    for (int mt = 0; mt < 4; mt++) {
#pragma unroll
        for (int r = 0; r < 4; r++) {
            int row = mt * 16 + quad * 4 + r;
            int rr = row >> 3, rc = row & 7;
            int regr = region_of(wh, ww, row);
            float sv[4]; float mx = -1e30f;
#pragma unroll
            for (int ct = 0; ct < 4; ct++) {
                float bias = blds[((rr - colr[ct] + 7) * 15 + (rc - colc[ct] + 7)) * 4 + head];
                float v = (regr == regc[ct])
                        ? fminf(fmaxf(s[mt][ct][r] + bias, -10.0f), 10.0f) : -10.0f;
                sv[ct] = v; mx = fmaxf(mx, v);
            }
#pragma unroll
            for (int m = 1; m < 16; m <<= 1) mx = fmaxf(mx, __shfl_xor(mx, m));
            float sum = 0.f;
#pragma unroll
            for (int ct = 0; ct < 4; ct++) { sv[ct] = __expf(sv[ct] - mx); sum += sv[ct]; }
#pragma unroll
            for (int m = 1; m < 16; m <<= 1) sum += __shfl_xor(sum, m);
            float inv = 1.0f / sum;
#pragma unroll
            for (int ct = 0; ct < 4; ct++)
                pm[head][row * 72 + ct * 16 + l15] = f2bf(sv[ct] * inv);
        }
    }
    __syncthreads();
    // O = P @ V
    f32x4 o[4][2];
#pragma unroll
    for (int mt = 0; mt < 4; mt++) { o[mt][0] = zero; o[mt][1] = zero; }
#pragma unroll
    for (int kb = 0; kb < 2; kb++) {
        bf16x8 ap[4];
#pragma unroll
        for (int mt = 0; mt < 4; mt++)
            ap[mt] = ldfrag(&pm[head][(mt * 16 + l15) * 72 + kb * 32 + quad * 8]);
        bf16x8 bv0 = ldfrag(&vt[head][l15 * 72 + kb * 32 + quad * 8]);
        bf16x8 bv1 = (l15 < 8) ? ldfrag(&vt[head][(16 + l15) * 72 + kb * 32 + quad * 8]) : zfrag();
#pragma unroll
        for (int mt = 0; mt < 4; mt++) {
            o[mt][0] = __builtin_amdgcn_mfma_f32_16x16x32_bf16(ap[mt], bv0, o[mt][0], 0, 0, 0);
            o[mt][1] = __builtin_amdgcn_mfma_f32_16x16x32_bf16(ap[mt], bv1, o[mt][1], 0, 0, 0);
        }
    }
#pragma unroll
    for (int ct2 = 0; ct2 < 2; ct2++) {
        int d = ct2 * 16 + l15;
        if (d < 24) {
#pragma unroll
            for (int mt = 0; mt < 4; mt++)
#pragma unroll
                for (int r = 0; r < 4; r++) {
                    int tok = mt * 16 + quad * 4 + r;
                    aout[((size_t)win * 64 + tok) * 96 + head * 24 + d] = f2bf(o[mt][ct2][r]);
                }
        }
    }
}

// ------- kernel 4: proj GEMM + window reverse + roll(+4,+4) + residual + fused LN2 -------
// writes x1 (bf16) and h_norm (bf16), both in natural token order
__global__ __launch_bounds__(256) void k_proj(const u16* __restrict__ aout,
                                              const u16* __restrict__ wT,
                                              const float* __restrict__ pb,
                                              const float* __restrict__ x,
                                              const float* __restrict__ g2,
                                              const float* __restrict__ b2,
                                              u16* __restrict__ x1b,
                                              u16* __restrict__ hnb) {
    __shared__ __align__(16) u16 wlds[96 * 104];
    {
        const int4* src = reinterpret_cast<const int4*>(wT);
        for (int i = threadIdx.x; i < 96 * 12; i += 256) {
            int row = i / 12, j = i - row * 12;
            *reinterpret_cast<int4*>(&wlds[row * 104 + j * 8]) = src[i];
        }
    }
    __syncthreads();
    const int wave = threadIdx.x >> 6, lane = threadIdx.x & 63;
    const int l15 = lane & 15, quad = lane >> 4;
    const int rowbase = blockIdx.x * 128 + wave * 32;
    f32x4 zero = {0.f, 0.f, 0.f, 0.f};
    f32x4 acc[2][6];
#pragma unroll
    for (int mt = 0; mt < 2; mt++)
#pragma unroll
        for (int ct = 0; ct < 6; ct++) acc[mt][ct] = zero;
#pragma unroll
    for (int kb = 0; kb < 96; kb += 32) {
        bf16x8 a0 = ldfrag(aout + (size_t)(rowbase + l15) * 96 + kb + quad * 8);
        bf16x8 a1 = ldfrag(aout + (size_t)(rowbase + 16 + l15) * 96 + kb + quad * 8);
#pragma unroll
        for (int ct = 0; ct < 6; ct++) {
            bf16x8 bf = ldfrag(&wlds[(ct * 16 + l15) * 104 + kb + quad * 8]);
            acc[0][ct] = __builtin_amdgcn_mfma_f32_16x16x32_bf16(a0, bf, acc[0][ct], 0, 0, 0);
            acc[1][ct] = __builtin_amdgcn_mfma_f32_16x16x32_bf16(a1, bf, acc[1][ct], 0, 0, 0);
        }
    }
    float pbv[6], gv[6], bv[6];
#pragma unroll
    for (int ct = 0; ct < 6; ct++) {
        int col = ct * 16 + l15;
        pbv[ct] = pb[col]; gv[ct] = g2[col]; bv[ct] = b2[col];
    }
#pragma unroll
    for (int mt = 0; mt < 2; mt++)
#pragma unroll
        for (int r = 0; r < 4; r++) {
            int wtok = rowbase + mt * 16 + quad * 4 + r;
            int win = wtok >> 6, n = wtok & 63;
            int b_ = win >> 10, wh = (win >> 5) & 31, ww = win & 31;
            int h0 = (wh * 8 + (n >> 3) + 4) & 255;
            int w0 = (ww * 8 + (n & 7) + 4) & 255;
            size_t obase = ((size_t)(b_ * 256 + h0) * 256 + w0) * 96;
            float v[6], s = 0.f, q = 0.f;
#pragma unroll
            for (int ct = 0; ct < 6; ct++) {
                v[ct] = acc[mt][ct][r] + pbv[ct] + x[obase + ct * 16 + l15];
                s += v[ct]; q += v[ct] * v[ct];
            }
#pragma unroll
            for (int m = 1; m < 16; m <<= 1) { s += __shfl_xor(s, m); q += __shfl_xor(q, m); }
            float mean = s * (1.0f / 96.0f);
            float var  = q * (1.0f / 96.0f) - mean * mean;
            float rstd = rsqrtf(var + 1e-5f);
#pragma unroll
            for (int ct = 0; ct < 6; ct++) {
                size_t o = obase + ct * 16 + l15;
                x1b[o] = f2bf(v[ct]);
                hnb[o] = f2bf((v[ct] - mean) * rstd * gv[ct] + bv[ct]);
            }
        }
}

// ------- kernel 5: fused MLP, weights LDS-resident with W1->W2 swap -------
// gelu(h@W1+b1)@W2+b2 + x1 -> d_out.  512 threads, 64 tokens/block.
__global__ __launch_bounds__(512) void k_mlp(const u16* __restrict__ hn,
                                             const u16* __restrict__ w1T,
                                             const float* __restrict__ b1,
                                             const u16* __restrict__ w2T,
                                             const float* __restrict__ b2,
                                             const u16* __restrict__ x1b,
                                             float* __restrict__ out) {
    __shared__ __align__(16) u16 wbuf[384 * 104];  // W1 [384][104] then W2 [96][392]
    __shared__ __align__(16) u16 mid[64 * 392];    // 64 tokens x 384, stride 392
    const int tid = threadIdx.x;
    // stage W1 with pad re-stride: 384 rows x 12 int4
    {
        const int4* src = reinterpret_cast<const int4*>(w1T);
        for (int i = tid; i < 384 * 12; i += 512) {
            int row = i / 12, j = i - row * 12;
            *reinterpret_cast<int4*>(&wbuf[row * 104 + j * 8]) = src[i];
        }
    }
    __syncthreads();
    const int wave = tid >> 6, lane = tid & 63;
    const int l15 = lane & 15, quad = lane >> 4;
    const int tg = wave & 3;        // token group (16 tokens)
    const int cs = wave >> 2;       // column split
    const int tok0 = blockIdx.x * 64 + tg * 16;
    f32x4 zero = {0.f, 0.f, 0.f, 0.f};
    // ---- gemm1: mid[:, cs*192 .. +192) ----
    f32x4 acc1[12];
#pragma unroll
    for (int ct = 0; ct < 12; ct++) acc1[ct] = zero;
#pragma unroll
    for (int kb = 0; kb < 3; kb++) {
        bf16x8 a = ldfrag(hn + (size_t)(tok0 + l15) * 96 + kb * 32 + quad * 8);
#pragma unroll
        for (int ct = 0; ct < 12; ct++) {
            bf16x8 bf = ldfrag(&wbuf[(cs * 192 + ct * 16 + l15) * 104 + kb * 32 + quad * 8]);
            acc1[ct] = __builtin_amdgcn_mfma_f32_16x16x32_bf16(a, bf, acc1[ct], 0, 0, 0);
        }
    }
#pragma unroll
    for (int ct = 0; ct < 12; ct++) {
        int col = cs * 192 + ct * 16 + l15;
        float bb = b1[col];
#pragma unroll
        for (int r = 0; r < 4; r++) {
            float v = acc1[ct][r] + bb;
            float gl = 0.5f * v * (1.0f + erff(v * 0.70710678118654752f));
            mid[(tg * 16 + quad * 4 + r) * 392 + col] = f2bf(gl);
        }
    }
    __syncthreads();   // all mid written, all W1 reads done
    // stage W2: 96 rows x 48 int4 -> stride 392
    {
        const int4* src = reinterpret_cast<const int4*>(w2T);
        for (int i = tid; i < 96 * 48; i += 512) {
            int row = i / 48, j = i - row * 48;
            *reinterpret_cast<int4*>(&wbuf[row * 392 + j * 8]) = src[i];
        }
    }
    __syncthreads();
    // ---- gemm2: out[:, cs*48 .. +48), K=384 ----
    f32x4 acc2[3];
#pragma unroll
    for (int ct = 0; ct < 3; ct++) acc2[ct] = zero;
#pragma unroll
    for (int kb2 = 0; kb2 < 12; kb2++) {
        bf16x8 a = ldfrag(&mid[(tg * 16 + l15) * 392 + kb2 * 32 + quad * 8]);
#pragma unroll
        for (int ct = 0; ct < 3; ct++) {
            bf16x8 bf = ldfrag(&wbuf[(cs * 48 + ct * 16 + l15) * 392 + kb2 * 32 + quad * 8]);
            acc2[ct] = __builtin_amdgcn_mfma_f32_16x16x32_bf16(a, bf, acc2[ct], 0, 0, 0);
        }
    }
#pragma unroll
    for (int ct = 0; ct < 3; ct++) {
        int col = cs * 48 + ct * 16 + l15;
        float bb = b2[col];
#pragma unroll
        for (int r = 0; r < 4; r++) {
            size_t o = (size_t)(tok0 + quad * 4 + r) * 96 + col;
            out[o] = acc2[ct][r] + bb + bf2f(x1b[o]);
        }
    }
}

extern "C" void kernel_launch(void* const* d_in, const int* in_sizes, int n_in,
                              void* d_out, int out_size, void* d_ws, size_t ws_size,
                              hipStream_t stream) {
    const float* x      = (const float*)d_in[0];
    const float* n1g    = (const float*)d_in[1];
    const float* n1b    = (const float*)d_in[2];
    const float* qkv_w  = (const float*)d_in[3];
    const float* qkv_b  = (const float*)d_in[4];
    const float* btab   = (const float*)d_in[5];
    const float* proj_w = (const float*)d_in[6];
    const float* proj_b = (const float*)d_in[7];
    const float* n2g    = (const float*)d_in[8];
    const float* n2b    = (const float*)d_in[9];
    const float* w1     = (const float*)d_in[10];
    const float* b1     = (const float*)d_in[11];
    const float* w2     = (const float*)d_in[12];
    const float* b2     = (const float*)d_in[13];
    float* out = (float*)d_out;
    char* ws = (char*)d_ws;

    // region 0 (0..302MB): qkvb during qkv/attn phase; then x1b+hnb (bf16) after
    u16* qkvb  = (u16*)(ws);                  // 524288*288*2 = 301,989,888
    u16* x1b   = (u16*)(ws);                  // 100,663,296 (reuses qkvb after attn)
    u16* hnb   = (u16*)(ws + 100663296);      // 100,663,296
    u16* tokb  = (u16*)(ws + 301989888);      // 100,663,296 (yw -> attn_out)
    u16* qkvT  = (u16*)(ws + 402653184);      // 288*96*2 = 55,296
    u16* projT = (u16*)(ws + 402708480);      // 96*96*2  = 18,432
    u16* w1T   = (u16*)(ws + 402726912);      // 384*96*2 = 73,728
    u16* w2T   = (u16*)(ws + 402800640);      // 96*384*2 = 73,728 (end 402,874,368)

    k_convert<<<144, 256, 0, stream>>>(qkv_w, proj_w, w1, w2, qkvT, projT, w1T, w2T);
    k_ln1<<<NTOK / 4, 256, 0, stream>>>(x, n1g, n1b, tokb);
    k_qkv<<<NTOK / 128, 256, 0, stream>>>(tokb, qkvT, qkv_b, qkvb);
    k_attn<<<NWIN, 256, 0, stream>>>(qkvb, btab, tokb);
    k_proj<<<NTOK / 128, 256, 0, stream>>>(tokb, projT, proj_b, x, n2g, n2b, x1b, hnb);
    k_mlp<<<NTOK / 64, 512, 0, stream>>>(hnb, w1T, b1, w2T, b2, x1b, out);
}